// Round 1
// baseline (1323.003 us; speedup 1.0000x reference)
//
#include <hip/hip_runtime.h>

// ---------------------------------------------------------------------------
// LSTM forecaster: 2-layer encoder (T=20) + 2-layer decoder (T=30, feedback).
// B=16384, H=128, F=10. Batch-partitioned: 256 blocks x 64 samples, whole
// recurrence per block. bf16 MFMA 16x16x32, fp32 accum, fp32 elementwise.
// ---------------------------------------------------------------------------

typedef __attribute__((ext_vector_type(8))) short short8;   // 8 x bf16 frag
typedef __attribute__((ext_vector_type(4))) float float4v;  // 4 x f32 acc

#define MFMA16(a, b, c) __builtin_amdgcn_mfma_f32_16x16x32_bf16((a), (b), (c), 0, 0, 0)

__device__ __forceinline__ unsigned short f2bf(float x) {
    unsigned u = __builtin_bit_cast(unsigned, x);
    unsigned r = (u + 0x7FFFu + ((u >> 16) & 1u)) >> 16;  // RNE
    return (unsigned short)r;
}
__device__ __forceinline__ float bf2f(unsigned short b) {
    unsigned u = ((unsigned)b) << 16;
    return __builtin_bit_cast(float, u);
}

#if __has_builtin(__builtin_amdgcn_exp2f)
__device__ __forceinline__ float vexp2(float x) { return __builtin_amdgcn_exp2f(x); }
#else
__device__ __forceinline__ float vexp2(float x) { return exp2f(x); }
#endif
#if __has_builtin(__builtin_amdgcn_rcpf)
__device__ __forceinline__ float vrcp(float x) { return __builtin_amdgcn_rcpf(x); }
#else
__device__ __forceinline__ float vrcp(float x) { return 1.0f / x; }
#endif

__device__ __forceinline__ float sigm(float x) {
    return vrcp(1.0f + vexp2(x * -1.442695040888963f));
}
__device__ __forceinline__ float tanh_(float x) {
    return 1.0f - 2.0f * vrcp(1.0f + vexp2(x * 2.885390081777927f));
}

// ---------------------------------------------------------------------------
// prep kernel: fp32 weights -> bf16, concatenated per-layer [Wih | Whh],
// Wih0 padded 10->32; biases summed. All into d_ws.
// ws layout (bf16 elems): We0[512][160] | We1[512][256] | Wd0[512][128] |
//                          Wd1[512][256] | f32 bsum[4][512]
// ---------------------------------------------------------------------------
__global__ void prep_kernel(const float* __restrict__ eWih0, const float* __restrict__ eWhh0,
                            const float* __restrict__ ebih0, const float* __restrict__ ebhh0,
                            const float* __restrict__ eWih1, const float* __restrict__ eWhh1,
                            const float* __restrict__ ebih1, const float* __restrict__ ebhh1,
                            const float* __restrict__ dWhh0,
                            const float* __restrict__ dbih0, const float* __restrict__ dbhh0,
                            const float* __restrict__ dWih1, const float* __restrict__ dWhh1,
                            const float* __restrict__ dbih1, const float* __restrict__ dbhh1,
                            void* __restrict__ ws)
{
    int i = blockIdx.x * 256 + threadIdx.x;
    short* We0 = (short*)ws;
    short* We1 = We0 + 512 * 160;
    short* Wd0 = We1 + 512 * 256;
    short* Wd1 = Wd0 + 512 * 128;
    float* bs  = (float*)(Wd1 + 512 * 256);
    const int N0 = 512 * 160, N1 = 512 * 256, N2 = 512 * 128, N3 = 512 * 256;
    if (i < N0) {
        int n = i / 160, k = i - n * 160;
        float v = (k < 32) ? (k < 10 ? eWih0[n * 10 + k] : 0.0f) : eWhh0[n * 128 + (k - 32)];
        We0[i] = (short)f2bf(v);
    } else if (i < N0 + N1) {
        int ii = i - N0, n = ii >> 8, k = ii & 255;
        float v = (k < 128) ? eWih1[n * 128 + k] : eWhh1[n * 128 + (k - 128)];
        We1[ii] = (short)f2bf(v);
    } else if (i < N0 + N1 + N2) {
        int ii = i - (N0 + N1);
        Wd0[ii] = (short)f2bf(dWhh0[ii]);
    } else if (i < N0 + N1 + N2 + N3) {
        int ii = i - (N0 + N1 + N2), n = ii >> 8, k = ii & 255;
        float v = (k < 128) ? dWih1[n * 128 + k] : dWhh1[n * 128 + (k - 128)];
        Wd1[ii] = (short)f2bf(v);
    } else if (i < N0 + N1 + N2 + N3 + 2048) {
        int ii = i - (N0 + N1 + N2 + N3);
        int g = ii >> 9, r = ii & 511;
        float v = (g == 0) ? ebih0[r] + ebhh0[r]
                : (g == 1) ? ebih1[r] + ebhh1[r]
                : (g == 2) ? dbih0[r] + dbhh0[r]
                           : dbih1[r] + dbhh1[r];
        bs[ii] = v;
    }
}

// ---------------------------------------------------------------------------
// main kernel
// LDS h-buffers: slot(m, kc) = m*16 + (kc ^ (m&15)), 16B chunks (kc = k>>3)
// xbuf:          slot(m, kc) = m*4  + (kc ^ (m&3))
// Wave w: all 4 m-tiles x n-tiles {w, w+8, w+16, w+24}  (q = gate i/f/g/o)
// A-frag: A[m = mt*16 + (lane&15)][k = (lane>>4)*8 + j]
// B-frag: B row n = 16*(w+8q) + (lane&15), k-chunk (lane>>4)*8
// C/D:    col = lane&15 (gate within tile), row = (lane>>4)*4 + reg (batch)
// ---------------------------------------------------------------------------

template <int NKT>
__device__ __forceinline__ void mma_block(float4v acc[4][4], const short8* __restrict__ hb,
                                          int woff0,
                                          const char* wq0, const char* wq1,
                                          const char* wq2, const char* wq3,
                                          int nib, int quad)
{
#pragma unroll
    for (int kk = 0; kk < NKT; ++kk) {
        int sx = ((kk * 4 + quad) ^ nib) + nib * 16;
        short8 a0 = hb[sx];
        short8 a1 = hb[256 + sx];
        short8 a2 = hb[512 + sx];
        short8 a3 = hb[768 + sx];
        short8 b0 = *(const short8*)(wq0 + woff0 + kk * 64);
        short8 b1 = *(const short8*)(wq1 + woff0 + kk * 64);
        short8 b2 = *(const short8*)(wq2 + woff0 + kk * 64);
        short8 b3 = *(const short8*)(wq3 + woff0 + kk * 64);
        acc[0][0] = MFMA16(a0, b0, acc[0][0]);
        acc[0][1] = MFMA16(a1, b0, acc[0][1]);
        acc[0][2] = MFMA16(a2, b0, acc[0][2]);
        acc[0][3] = MFMA16(a3, b0, acc[0][3]);
        acc[1][0] = MFMA16(a0, b1, acc[1][0]);
        acc[1][1] = MFMA16(a1, b1, acc[1][1]);
        acc[1][2] = MFMA16(a2, b1, acc[1][2]);
        acc[1][3] = MFMA16(a3, b1, acc[1][3]);
        acc[2][0] = MFMA16(a0, b2, acc[2][0]);
        acc[2][1] = MFMA16(a1, b2, acc[2][1]);
        acc[2][2] = MFMA16(a2, b2, acc[2][2]);
        acc[2][3] = MFMA16(a3, b2, acc[2][3]);
        acc[3][0] = MFMA16(a0, b3, acc[3][0]);
        acc[3][1] = MFMA16(a1, b3, acc[3][1]);
        acc[3][2] = MFMA16(a2, b3, acc[3][2]);
        acc[3][3] = MFMA16(a3, b3, acc[3][3]);
    }
}

// elementwise LSTM cell update; writes h (bf16) to hdst with swizzled layout
template <bool DEC0>
__device__ __forceinline__ void cell_update(float4v acc[4][4], const float bi[4],
                                            float* cst, unsigned short* hdst,
                                            const float* ybuf, const float* wy,
                                            int w, int nib, int quad)
{
    int j = 16 * w + nib;
    int kc = j >> 3;
    int jl = j & 7;
#pragma unroll
    for (int mt = 0; mt < 4; ++mt) {
#pragma unroll
        for (int r = 0; r < 4; ++r) {
            float gi = acc[0][mt][r] + bi[0];
            float gf = acc[1][mt][r] + bi[1];
            float gg = acc[2][mt][r] + bi[2];
            float go = acc[3][mt][r] + bi[3];
            int m = mt * 16 + quad * 4 + r;
            if (DEC0) {
                float y0 = ybuf[2 * m], y1 = ybuf[2 * m + 1];
                gi += y0 * wy[0] + y1 * wy[1];
                gf += y0 * wy[2] + y1 * wy[3];
                gg += y0 * wy[4] + y1 * wy[5];
                go += y0 * wy[6] + y1 * wy[7];
            }
            float si = sigm(gi);
            float sf = sigm(gf);
            float tg = tanh_(gg);
            float so = sigm(go);
            float c = sf * cst[mt * 4 + r] + si * tg;
            cst[mt * 4 + r] = c;
            float h = so * tanh_(c);
            int slot = m * 16 + (kc ^ (m & 15));
            hdst[slot * 8 + jl] = f2bf(h);
        }
    }
}

__global__ __launch_bounds__(512, 2) void lstm_main(
    const float* __restrict__ hist, const float* __restrict__ dWih0,
    const float* __restrict__ headW, const float* __restrict__ headB,
    const int* __restrict__ futlen, const void* __restrict__ ws,
    float* __restrict__ out)
{
    __shared__ short8 h0buf[1024];  // [64 rows][16 chunks] swizzled
    __shared__ short8 h1buf[1024];
    __shared__ short8 xbuf[256];    // [64 rows][4 chunks]  swizzled
    __shared__ float ybuf[128];     // [64][2]

    const short* We0 = (const short*)ws;
    const short* We1 = We0 + 512 * 160;
    const short* Wd0 = We1 + 512 * 256;
    const short* Wd1 = Wd0 + 512 * 128;
    const float* bs = (const float*)(Wd1 + 512 * 256);
    const float* be0 = bs;
    const float* be1 = bs + 512;
    const float* bd0 = bs + 1024;
    const float* bd1 = bs + 1536;

    const int tid = threadIdx.x;
    const int w = tid >> 6;
    const int lane = tid & 63;
    const int quad = lane >> 4;
    const int nib = lane & 15;
    const int b0 = blockIdx.x * 64;
    const int TFUT = *futlen;
    const int j = 16 * w + nib;

    // zero-init LDS state
    for (int i = tid; i < 1024; i += 512) {
        h0buf[i] = (short8)0;
        h1buf[i] = (short8)0;
    }
    if (tid < 256) xbuf[tid] = (short8)0;
    if (tid < 128) ybuf[tid] = 0.0f;

    float c0[16], c1[16];
#pragma unroll
    for (int i = 0; i < 16; ++i) { c0[i] = 0.0f; c1[i] = 0.0f; }

    // per-lane B-fragment row pointers (row = 16*(w+8q)+nib, + quad*16B k-chunk)
    const char *e0q0, *e0q1, *e0q2, *e0q3, *e1q0, *e1q1, *e1q2, *e1q3;
    {
        e0q0 = (const char*)(We0 + (16 * (w + 0)  + nib) * 160) + quad * 16;
        e0q1 = (const char*)(We0 + (16 * (w + 8)  + nib) * 160) + quad * 16;
        e0q2 = (const char*)(We0 + (16 * (w + 16) + nib) * 160) + quad * 16;
        e0q3 = (const char*)(We0 + (16 * (w + 24) + nib) * 160) + quad * 16;
        e1q0 = (const char*)(We1 + (16 * (w + 0)  + nib) * 256) + quad * 16;
        e1q1 = (const char*)(We1 + (16 * (w + 8)  + nib) * 256) + quad * 16;
        e1q2 = (const char*)(We1 + (16 * (w + 16) + nib) * 256) + quad * 16;
        e1q3 = (const char*)(We1 + (16 * (w + 24) + nib) * 256) + quad * 16;
    }
    float bE0v[4], bE1v[4];
#pragma unroll
    for (int q = 0; q < 4; ++q) {
        bE0v[q] = be0[128 * q + j];
        bE1v[q] = be1[128 * q + j];
    }
    __syncthreads();

    // ================= ENCODER =================
    for (int t = 0; t < 20; ++t) {
        // stage hist[.., t, :] -> xbuf (bf16, zero-padded to K=32)
        if (tid < 128) {
            int m = tid & 63, part = tid >> 6;  // part: k-chunk 0 or 1
            const float* hp = hist + ((size_t)((b0 + m) * 20 + t)) * 10;
            float v[8];
            if (part == 0) {
#pragma unroll
                for (int i = 0; i < 8; ++i) v[i] = hp[i];
            } else {
                v[0] = hp[8]; v[1] = hp[9];
#pragma unroll
                for (int i = 2; i < 8; ++i) v[i] = 0.0f;
            }
            short8 pk;
#pragma unroll
            for (int i = 0; i < 8; ++i) pk[i] = (short)f2bf(v[i]);
            xbuf[m * 4 + (part ^ (m & 3))] = pk;
        }
        __syncthreads();

        // ---- layer 0: gates = x@Wih0^T + h0@Whh0^T ----
        {
            float4v acc[4][4];
#pragma unroll
            for (int q = 0; q < 4; ++q)
#pragma unroll
                for (int mt = 0; mt < 4; ++mt) acc[q][mt] = (float4v){0.f, 0.f, 0.f, 0.f};
            // x part (k 0..31) from xbuf
            {
                int sxx = (quad ^ (nib & 3)) + nib * 4;
                short8 a0 = xbuf[sxx];
                short8 a1 = xbuf[64 + sxx];
                short8 a2 = xbuf[128 + sxx];
                short8 a3 = xbuf[192 + sxx];
                short8 bq0 = *(const short8*)(e0q0);
                short8 bq1 = *(const short8*)(e0q1);
                short8 bq2 = *(const short8*)(e0q2);
                short8 bq3 = *(const short8*)(e0q3);
                acc[0][0] = MFMA16(a0, bq0, acc[0][0]);
                acc[0][1] = MFMA16(a1, bq0, acc[0][1]);
                acc[0][2] = MFMA16(a2, bq0, acc[0][2]);
                acc[0][3] = MFMA16(a3, bq0, acc[0][3]);
                acc[1][0] = MFMA16(a0, bq1, acc[1][0]);
                acc[1][1] = MFMA16(a1, bq1, acc[1][1]);
                acc[1][2] = MFMA16(a2, bq1, acc[1][2]);
                acc[1][3] = MFMA16(a3, bq1, acc[1][3]);
                acc[2][0] = MFMA16(a0, bq2, acc[2][0]);
                acc[2][1] = MFMA16(a1, bq2, acc[2][1]);
                acc[2][2] = MFMA16(a2, bq2, acc[2][2]);
                acc[2][3] = MFMA16(a3, bq2, acc[2][3]);
                acc[3][0] = MFMA16(a0, bq3, acc[3][0]);
                acc[3][1] = MFMA16(a1, bq3, acc[3][1]);
                acc[3][2] = MFMA16(a2, bq3, acc[3][2]);
                acc[3][3] = MFMA16(a3, bq3, acc[3][3]);
            }
            // h part (W k 32..159) from h0buf
            mma_block<4>(acc, h0buf, 64, e0q0, e0q1, e0q2, e0q3, nib, quad);
            __syncthreads();
            cell_update<false>(acc, bE0v, c0, (unsigned short*)h0buf, nullptr, nullptr, w, nib, quad);
        }
        __syncthreads();

        // ---- layer 1: gates = h0new@Wih1^T + h1@Whh1^T ----
        {
            float4v acc[4][4];
#pragma unroll
            for (int q = 0; q < 4; ++q)
#pragma unroll
                for (int mt = 0; mt < 4; ++mt) acc[q][mt] = (float4v){0.f, 0.f, 0.f, 0.f};
            mma_block<4>(acc, h0buf, 0, e1q0, e1q1, e1q2, e1q3, nib, quad);
            mma_block<4>(acc, h1buf, 256, e1q0, e1q1, e1q2, e1q3, nib, quad);
            __syncthreads();
            cell_update<false>(acc, bE1v, c1, (unsigned short*)h1buf, nullptr, nullptr, w, nib, quad);
        }
        __syncthreads();
    }

    // ================= DECODER =================
    const char *d0q0, *d0q1, *d0q2, *d0q3, *d1q0, *d1q1, *d1q2, *d1q3;
    {
        d0q0 = (const char*)(Wd0 + (16 * (w + 0)  + nib) * 128) + quad * 16;
        d0q1 = (const char*)(Wd0 + (16 * (w + 8)  + nib) * 128) + quad * 16;
        d0q2 = (const char*)(Wd0 + (16 * (w + 16) + nib) * 128) + quad * 16;
        d0q3 = (const char*)(Wd0 + (16 * (w + 24) + nib) * 128) + quad * 16;
        d1q0 = (const char*)(Wd1 + (16 * (w + 0)  + nib) * 256) + quad * 16;
        d1q1 = (const char*)(Wd1 + (16 * (w + 8)  + nib) * 256) + quad * 16;
        d1q2 = (const char*)(Wd1 + (16 * (w + 16) + nib) * 256) + quad * 16;
        d1q3 = (const char*)(Wd1 + (16 * (w + 24) + nib) * 256) + quad * 16;
    }
    float bD0v[4], bD1v[4], wy[8];
#pragma unroll
    for (int q = 0; q < 4; ++q) {
        bD0v[q] = bd0[128 * q + j];
        bD1v[q] = bd1[128 * q + j];
        int g = 128 * q + j;
        wy[q * 2]     = dWih0[g * 2];
        wy[q * 2 + 1] = dWih0[g * 2 + 1];
    }

    for (int t = 0; t < TFUT; ++t) {
        // ---- dec layer 0: gates = y@dWih0^T (VALU) + h0@dWhh0^T (MFMA) ----
        {
            float4v acc[4][4];
#pragma unroll
            for (int q = 0; q < 4; ++q)
#pragma unroll
                for (int mt = 0; mt < 4; ++mt) acc[q][mt] = (float4v){0.f, 0.f, 0.f, 0.f};
            mma_block<4>(acc, h0buf, 0, d0q0, d0q1, d0q2, d0q3, nib, quad);
            __syncthreads();
            cell_update<true>(acc, bD0v, c0, (unsigned short*)h0buf, ybuf, wy, w, nib, quad);
        }
        __syncthreads();

        // ---- dec layer 1 ----
        {
            float4v acc[4][4];
#pragma unroll
            for (int q = 0; q < 4; ++q)
#pragma unroll
                for (int mt = 0; mt < 4; ++mt) acc[q][mt] = (float4v){0.f, 0.f, 0.f, 0.f};
            mma_block<4>(acc, h0buf, 0, d1q0, d1q1, d1q2, d1q3, nib, quad);
            mma_block<4>(acc, h1buf, 256, d1q0, d1q1, d1q2, d1q3, nib, quad);
            __syncthreads();
            cell_update<false>(acc, bD1v, c1, (unsigned short*)h1buf, nullptr, nullptr, w, nib, quad);
        }
        __syncthreads();

        // ---- head: y = h1new @ headW^T + headB; emit output & feedback ----
        if (tid < 128) {
            int m = tid & 63, jj = tid >> 6;
            float dot = headB[jj];
            int mk = m & 15;
#pragma unroll
            for (int kc = 0; kc < 16; ++kc) {
                short8 ch = h1buf[m * 16 + (kc ^ mk)];
#pragma unroll
                for (int i = 0; i < 8; ++i)
                    dot += bf2f((unsigned short)ch[i]) * headW[jj * 128 + kc * 8 + i];
            }
            ybuf[2 * m + jj] = dot;
            out[((size_t)(b0 + m) * TFUT + t) * 2 + jj] = dot;
        }
        __syncthreads();
    }
}

extern "C" void kernel_launch(void* const* d_in, const int* in_sizes, int n_in,
                              void* d_out, int out_size, void* d_ws, size_t ws_size,
                              hipStream_t stream)
{
    const float* hist   = (const float*)d_in[0];
    const float* eWih0  = (const float*)d_in[1];
    const float* eWhh0  = (const float*)d_in[2];
    const float* ebih0  = (const float*)d_in[3];
    const float* ebhh0  = (const float*)d_in[4];
    const float* eWih1  = (const float*)d_in[5];
    const float* eWhh1  = (const float*)d_in[6];
    const float* ebih1  = (const float*)d_in[7];
    const float* ebhh1  = (const float*)d_in[8];
    const float* dWih0  = (const float*)d_in[9];
    const float* dWhh0  = (const float*)d_in[10];
    const float* dbih0  = (const float*)d_in[11];
    const float* dbhh0  = (const float*)d_in[12];
    const float* dWih1  = (const float*)d_in[13];
    const float* dWhh1  = (const float*)d_in[14];
    const float* dbih1  = (const float*)d_in[15];
    const float* dbhh1  = (const float*)d_in[16];
    const float* headW  = (const float*)d_in[17];
    const float* headB  = (const float*)d_in[18];
    const int*   futlen = (const int*)d_in[19];

    // 512*160 + 512*256 + 512*128 + 512*256 bf16 + 4*512 f32 = 411648 elems
    prep_kernel<<<1608, 256, 0, stream>>>(eWih0, eWhh0, ebih0, ebhh0,
                                          eWih1, eWhh1, ebih1, ebhh1,
                                          dWhh0, dbih0, dbhh0,
                                          dWih1, dWhh1, dbih1, dbhh1, d_ws);

    lstm_main<<<256, 512, 0, stream>>>(hist, dWih0, headW, headB, futlen,
                                       d_ws, (float*)d_out);
}